// Round 4
// baseline (688.911 us; speedup 1.0000x reference)
//
#include <hip/hip_runtime.h>
#include <hip/hip_bf16.h>

#define NN 50000
#define EE 640000
#define FF 128
#define HH 128

typedef unsigned short ushort_t;
using f32x4  = __attribute__((ext_vector_type(4))) float;
using bf16x8 = __attribute__((ext_vector_type(8))) __bf16;
using u16x8  = __attribute__((ext_vector_type(8))) unsigned short;

__device__ __forceinline__ ushort_t f2bf(float f) {
    union { float f; unsigned int i; } v; v.f = f;
    unsigned int r = v.i + 0x7fffu + ((v.i >> 16) & 1u);
    return (ushort_t)(r >> 16);
}
__device__ __forceinline__ float fsilu(float x) { return x / (1.f + __expf(-x)); }
__device__ __forceinline__ float fsig(float x)  { return 1.f / (1.f + __expf(-x)); }

__device__ __forceinline__ u16x8 cvt8(const float* p) {
    float4 a0 = *reinterpret_cast<const float4*>(p);
    float4 a1 = *reinterpret_cast<const float4*>(p + 4);
    u16x8 v;
    v[0] = f2bf(a0.x); v[1] = f2bf(a0.y); v[2] = f2bf(a0.z); v[3] = f2bf(a0.w);
    v[4] = f2bf(a1.x); v[5] = f2bf(a1.y); v[6] = f2bf(a1.z); v[7] = f2bf(a1.w);
    return v;
}

// ---------------------------------------------------------------------------
// h f32 -> bf16 pre-pass
// ---------------------------------------------------------------------------
__global__ void cvt_h_kernel(const float* __restrict__ h, ushort_t* __restrict__ hbf)
{
    const int i = (blockIdx.x * 256 + threadIdx.x) * 8;
    if (i < NN * 128) {
        u16x8 v = cvt8(h + i);
        *reinterpret_cast<u16x8*>(hbf + i) = v;
    }
}

// ---------------------------------------------------------------------------
// CSR build: histogram -> scan -> scatter
// ---------------------------------------------------------------------------
__global__ void hist_kernel(const int* __restrict__ eidx, int* __restrict__ deg)
{
    const int e = blockIdx.x * 256 + threadIdx.x;
    if (e < EE) atomicAdd(&deg[eidx[e]], 1);
}

__global__ void scan_kernel(const int* __restrict__ deg, int* __restrict__ row_ptr,
                            int* __restrict__ cursor)
{
    __shared__ int sdata[1024];
    const int t = threadIdx.x;
    const int chunk = (NN + 1023) / 1024;   // 49
    const int start = t * chunk;
    const int end   = min(start + chunk, NN);
    int s = 0;
    for (int i = start; i < end; ++i) s += deg[i];
    sdata[t] = s;
    __syncthreads();
    for (int off = 1; off < 1024; off <<= 1) {
        int v = (t >= off) ? sdata[t - off] : 0;
        __syncthreads();
        sdata[t] += v;
        __syncthreads();
    }
    int ox = sdata[t] - s;   // exclusive prefix
    for (int i = start; i < end; ++i) {
        row_ptr[i] = ox; cursor[i] = ox; ox += deg[i];
    }
    if (t == 1023) row_ptr[NN] = sdata[1023];
}

__global__ void scatter_kernel(const int* __restrict__ eidx, int* __restrict__ cursor,
                               int* __restrict__ edge_list)
{
    const int e = blockIdx.x * 256 + threadIdx.x;
    if (e < EE) {
        const int r = eidx[e];
        const int p = atomicAdd(&cursor[r], 1);
        edge_list[p] = e;
    }
}

// ---------------------------------------------------------------------------
// Edge kernel, 64-edge tiles, NO atomics. Writes gated m and per-edge trans.
// Wave w owns output cols [32w,32w+32); gate computed per-wave for all edges
// via MFMA against [aW|pW2|0..].
// ---------------------------------------------------------------------------
__global__ __launch_bounds__(256, 2) void egcl_edge_kernel(
    const ushort_t* __restrict__ hbf, const float* __restrict__ pos,
    const int* __restrict__ eidx, const float* __restrict__ eattr,
    const float* __restrict__ w1, const float* __restrict__ b1,
    const float* __restrict__ w2, const float* __restrict__ b2,
    const float* __restrict__ aW, const float* __restrict__ ab,
    const float* __restrict__ pW2,
    float* __restrict__ m_out, float* __restrict__ trans_out)
{
    __shared__ __align__(16) ushort_t A_sh[64 * 296];
    __shared__ __align__(16) ushort_t M1_sh[64 * 136];
    __shared__ __align__(16) ushort_t M2_sh[64 * 136];
    __shared__ float PD_sh[64][3];

    const int tid  = threadIdx.x;
    const int lane = tid & 63;
    const int w    = tid >> 6;
    const int l15  = lane & 15;
    const int lg   = lane >> 4;

    // ---- weights in registers ----
    bf16x8 B1[9][2];
    bf16x8 B2[4][2];
    bf16x8 Bg[4];
    float b1c[2], b2c[2];
    const float abv = ab[0];
#pragma unroll
    for (int nt = 0; nt < 2; ++nt) {
        const int colg = 32 * w + 16 * nt + l15;
        b1c[nt] = b1[colg];
        b2c[nt] = b2[colg];
#pragma unroll
        for (int ks = 0; ks < 9; ++ks) {
            u16x8 v;
#pragma unroll
            for (int j = 0; j < 8; ++j) {
                const int k = 32 * ks + 8 * lg + j;
                v[j] = (k < 265) ? f2bf(w1[k * 128 + colg]) : (ushort_t)0;
            }
            B1[ks][nt] = __builtin_bit_cast(bf16x8, v);
        }
#pragma unroll
        for (int ks = 0; ks < 4; ++ks) {
            u16x8 v;
#pragma unroll
            for (int j = 0; j < 8; ++j) {
                const int k = 32 * ks + 8 * lg + j;
                v[j] = f2bf(w2[k * 128 + colg]);
            }
            B2[ks][nt] = __builtin_bit_cast(bf16x8, v);
        }
    }
#pragma unroll
    for (int ks = 0; ks < 4; ++ks) {
        u16x8 v;
#pragma unroll
        for (int j = 0; j < 8; ++j) {
            const int k = 32 * ks + 8 * lg + j;
            v[j] = (l15 == 0) ? f2bf(aW[k]) : (l15 == 1 ? f2bf(pW2[k]) : (ushort_t)0);
        }
        Bg[ks] = __builtin_bit_cast(bf16x8, v);
    }

    const int ei = tid >> 2;   // edge slot 0..63
    const int et = tid & 3;    // 4 threads/edge, 32 bf16 each per row

    for (int tile = blockIdx.x; tile < EE / 64; tile += gridDim.x) {
        // ---- stage (bf16 gather; no conversion needed) ----
        {
            const int e = tile * 64 + ei;
            const int r = eidx[e];
            const int c = eidx[EE + e];
            const ushort_t* hr = hbf + (size_t)r * 128 + et * 32;
            const ushort_t* hc = hbf + (size_t)c * 128 + et * 32;
#pragma unroll
            for (int q = 0; q < 4; ++q) {
                *reinterpret_cast<u16x8*>(&A_sh[ei * 296 + et * 32 + q * 8]) =
                    *reinterpret_cast<const u16x8*>(hr + q * 8);
                *reinterpret_cast<u16x8*>(&A_sh[ei * 296 + 128 + et * 32 + q * 8]) =
                    *reinterpret_cast<const u16x8*>(hc + q * 8);
            }
            if (et == 0) {
                const float dx = pos[r * 3 + 0] - pos[c * 3 + 0];
                const float dy = pos[r * 3 + 1] - pos[c * 3 + 1];
                const float dz = pos[r * 3 + 2] - pos[c * 3 + 2];
                PD_sh[ei][0] = dx; PD_sh[ei][1] = dy; PD_sh[ei][2] = dz;
                const float ds = dx * dx + dy * dy + dz * dz;
                u16x8 v0;
                v0[0] = f2bf(ds);
#pragma unroll
                for (int j = 0; j < 7; ++j) v0[1 + j] = f2bf(eattr[e * 8 + j]);
                *reinterpret_cast<u16x8*>(&A_sh[ei * 296 + 256]) = v0;
                u16x8 v1 = {0, 0, 0, 0, 0, 0, 0, 0};
                v1[0] = f2bf(eattr[e * 8 + 7]);
                *reinterpret_cast<u16x8*>(&A_sh[ei * 296 + 264]) = v1;
                u16x8 z = {0, 0, 0, 0, 0, 0, 0, 0};
                *reinterpret_cast<u16x8*>(&A_sh[ei * 296 + 272]) = z;
                *reinterpret_cast<u16x8*>(&A_sh[ei * 296 + 280]) = z;
            }
        }
        __syncthreads();                       // B1: A ready

        // ---- layer 1 ----
#pragma unroll
        for (int s = 0; s < 4; ++s) {
            f32x4 a0 = {0.f, 0.f, 0.f, 0.f};
            f32x4 a1 = {0.f, 0.f, 0.f, 0.f};
#pragma unroll
            for (int ks = 0; ks < 9; ++ks) {
                bf16x8 a = *reinterpret_cast<const bf16x8*>(
                    &A_sh[(16 * s + l15) * 296 + ks * 32 + lg * 8]);
                a0 = __builtin_amdgcn_mfma_f32_16x16x32_bf16(a, B1[ks][0], a0, 0, 0, 0);
                a1 = __builtin_amdgcn_mfma_f32_16x16x32_bf16(a, B1[ks][1], a1, 0, 0, 0);
            }
#pragma unroll
            for (int nt = 0; nt < 2; ++nt) {
#pragma unroll
                for (int rr = 0; rr < 4; ++rr) {
                    const float x = (nt == 0 ? a0[rr] : a1[rr]) + b1c[nt];
                    const int edge = 16 * s + 4 * lg + rr;
                    const int colg = 32 * w + 16 * nt + l15;
                    M1_sh[edge * 136 + colg] = f2bf(fsilu(x));
                }
            }
        }
        __syncthreads();                       // B2: M1 ready (A reads done)

        // ---- layer 2 ----
        float m2v[4][2][4];
#pragma unroll
        for (int s = 0; s < 4; ++s) {
            f32x4 a0 = {0.f, 0.f, 0.f, 0.f};
            f32x4 a1 = {0.f, 0.f, 0.f, 0.f};
#pragma unroll
            for (int ks = 0; ks < 4; ++ks) {
                bf16x8 a = *reinterpret_cast<const bf16x8*>(
                    &M1_sh[(16 * s + l15) * 136 + ks * 32 + lg * 8]);
                a0 = __builtin_amdgcn_mfma_f32_16x16x32_bf16(a, B2[ks][0], a0, 0, 0, 0);
                a1 = __builtin_amdgcn_mfma_f32_16x16x32_bf16(a, B2[ks][1], a1, 0, 0, 0);
            }
#pragma unroll
            for (int nt = 0; nt < 2; ++nt) {
#pragma unroll
                for (int rr = 0; rr < 4; ++rr) {
                    const float x = (nt == 0 ? a0[rr] : a1[rr]) + b2c[nt];
                    const float sv = fsilu(x);
                    m2v[s][nt][rr] = sv;
                    const int edge = 16 * s + 4 * lg + rr;
                    const int colg = 32 * w + 16 * nt + l15;
                    M2_sh[edge * 136 + colg] = f2bf(sv);
                }
            }
        }
        __syncthreads();                       // B3: M2 ready

        // ---- gate (per-wave, all subtiles) + trans write (own subtile) ----
        float gq[4][4];
#pragma unroll
        for (int s = 0; s < 4; ++s) {
            f32x4 ga = {0.f, 0.f, 0.f, 0.f};
#pragma unroll
            for (int ks = 0; ks < 4; ++ks) {
                bf16x8 a = *reinterpret_cast<const bf16x8*>(
                    &M2_sh[(16 * s + l15) * 136 + ks * 32 + lg * 8]);
                ga = __builtin_amdgcn_mfma_f32_16x16x32_bf16(a, Bg[ks], ga, 0, 0, 0);
            }
#pragma unroll
            for (int rr = 0; rr < 4; ++rr) {
                const float sa = __shfl(ga[rr], lane & 48);
                gq[s][rr] = fsig(sa + abv);
                if (s == w) {
                    const float sp = __shfl(ga[rr], (lane & 48) + 1);
                    if (l15 == 0) {
                        const int edge = 16 * w + 4 * lg + rr;
                        const float t = gq[s][rr] * sp;
                        const size_t e = (size_t)tile * 64 + edge;
                        trans_out[e * 3 + 0] = PD_sh[edge][0] * t;
                        trans_out[e * 3 + 1] = PD_sh[edge][1] * t;
                        trans_out[e * 3 + 2] = PD_sh[edge][2] * t;
                    }
                }
            }
        }

        // ---- gated m write (no barrier needed; next stage only touches A/PD
        //      which are written/read by the same wave or protected by B1) ----
#pragma unroll
        for (int s = 0; s < 4; ++s) {
#pragma unroll
            for (int nt = 0; nt < 2; ++nt) {
#pragma unroll
                for (int rr = 0; rr < 4; ++rr) {
                    const int edge = 16 * s + 4 * lg + rr;
                    const int colg = 32 * w + 16 * nt + l15;
                    const size_t e = (size_t)tile * 64 + edge;
                    m_out[e * 128 + colg] = m2v[s][nt][rr] * gq[s][rr];
                }
            }
        }
        __syncthreads();                       // protect M2 (gate reads) + A from next stage
    }
}

// ---------------------------------------------------------------------------
// Fused node kernel: CSR-gather agg + pos update + node MLP + residual.
// ---------------------------------------------------------------------------
__global__ __launch_bounds__(256, 3) void egcl_node_kernel(
    const ushort_t* __restrict__ hbf, const float* __restrict__ h,
    const float* __restrict__ m_src, const float* __restrict__ trans,
    const int* __restrict__ row_ptr, const int* __restrict__ edge_list,
    const float* __restrict__ pos,
    const float* __restrict__ w1, const float* __restrict__ b1,
    const float* __restrict__ w2, const float* __restrict__ b2,
    float* __restrict__ hn_out, float* __restrict__ pos_out)
{
    __shared__ __align__(16) ushort_t A_sh[16 * 264];
    __shared__ __align__(16) ushort_t M1_sh[16 * 136];

    const int tid  = threadIdx.x;
    const int lane = tid & 63;
    const int w    = tid >> 6;
    const int l15  = lane & 15;
    const int lg   = lane >> 4;

    bf16x8 B1[8][2];
    bf16x8 B2[4][2];
    float b1c[2], b2c[2];
#pragma unroll
    for (int nt = 0; nt < 2; ++nt) {
        const int colg = 32 * w + 16 * nt + l15;
        b1c[nt] = b1[colg];
        b2c[nt] = b2[colg];
#pragma unroll
        for (int ks = 0; ks < 8; ++ks) {
            u16x8 v;
#pragma unroll
            for (int j = 0; j < 8; ++j) {
                const int k = 32 * ks + 8 * lg + j;
                v[j] = f2bf(w1[k * 128 + colg]);
            }
            B1[ks][nt] = __builtin_bit_cast(bf16x8, v);
        }
#pragma unroll
        for (int ks = 0; ks < 4; ++ks) {
            u16x8 v;
#pragma unroll
            for (int j = 0; j < 8; ++j) {
                const int k = 32 * ks + 8 * lg + j;
                v[j] = f2bf(w2[k * 128 + colg]);
            }
            B2[ks][nt] = __builtin_bit_cast(bf16x8, v);
        }
    }

    const int ni = tid >> 4;
    const int nt16 = tid & 15;

    for (int tile = blockIdx.x; tile < NN / 16; tile += gridDim.x) {
        __syncthreads();
        const int base = tile * 16;

        // stage h rows (bf16 direct copy)
        *reinterpret_cast<u16x8*>(&A_sh[ni * 264 + nt16 * 8]) =
            *reinterpret_cast<const u16x8*>(hbf + (size_t)(base + ni) * 128 + nt16 * 8);

        // gather-aggregate: wave w handles nodes base+4w .. base+4w+3
#pragma unroll
        for (int q = 0; q < 4; ++q) {
            const int nl = 4 * w + q;
            const int n = base + nl;
            const int b = row_ptr[n];
            const int ce = row_ptr[n + 1] - b;
            float a0 = 0.f, a1 = 0.f, tacc = 0.f;
            int j = 0;
            for (; j + 1 < ce; j += 2) {
                const int e0 = edge_list[b + j];
                const int e1 = edge_list[b + j + 1];
                const float2 v0 = *reinterpret_cast<const float2*>(m_src + (size_t)e0 * 128 + 2 * lane);
                const float2 v1 = *reinterpret_cast<const float2*>(m_src + (size_t)e1 * 128 + 2 * lane);
                a0 += v0.x + v1.x;
                a1 += v0.y + v1.y;
                if (lane < 3) tacc += trans[(size_t)e0 * 3 + lane] + trans[(size_t)e1 * 3 + lane];
            }
            if (j < ce) {
                const int e0 = edge_list[b + j];
                const float2 v0 = *reinterpret_cast<const float2*>(m_src + (size_t)e0 * 128 + 2 * lane);
                a0 += v0.x; a1 += v0.y;
                if (lane < 3) tacc += trans[(size_t)e0 * 3 + lane];
            }
            A_sh[nl * 264 + 128 + 2 * lane]     = f2bf(a0);
            A_sh[nl * 264 + 128 + 2 * lane + 1] = f2bf(a1);
            if (lane < 3)
                pos_out[(size_t)n * 3 + lane] =
                    pos[(size_t)n * 3 + lane] + tacc / fmaxf((float)ce, 1.f);
        }
        __syncthreads();

        // ---- node MLP layer 1 ----
        f32x4 acc10 = {0.f, 0.f, 0.f, 0.f};
        f32x4 acc11 = {0.f, 0.f, 0.f, 0.f};
#pragma unroll
        for (int ks = 0; ks < 8; ++ks) {
            bf16x8 a = *reinterpret_cast<const bf16x8*>(&A_sh[l15 * 264 + ks * 32 + lg * 8]);
            acc10 = __builtin_amdgcn_mfma_f32_16x16x32_bf16(a, B1[ks][0], acc10, 0, 0, 0);
            acc11 = __builtin_amdgcn_mfma_f32_16x16x32_bf16(a, B1[ks][1], acc11, 0, 0, 0);
        }
#pragma unroll
        for (int nt = 0; nt < 2; ++nt) {
#pragma unroll
            for (int r = 0; r < 4; ++r) {
                const float x = (nt == 0 ? acc10[r] : acc11[r]) + b1c[nt];
                const int nl = 4 * lg + r;
                const int colg = 32 * w + 16 * nt + l15;
                M1_sh[nl * 136 + colg] = f2bf(fsilu(x));
            }
        }
        __syncthreads();

        // ---- node MLP layer 2 + residual ----
        f32x4 acc20 = {0.f, 0.f, 0.f, 0.f};
        f32x4 acc21 = {0.f, 0.f, 0.f, 0.f};
#pragma unroll
        for (int ks = 0; ks < 4; ++ks) {
            bf16x8 a = *reinterpret_cast<const bf16x8*>(&M1_sh[l15 * 136 + ks * 32 + lg * 8]);
            acc20 = __builtin_amdgcn_mfma_f32_16x16x32_bf16(a, B2[ks][0], acc20, 0, 0, 0);
            acc21 = __builtin_amdgcn_mfma_f32_16x16x32_bf16(a, B2[ks][1], acc21, 0, 0, 0);
        }
#pragma unroll
        for (int nt = 0; nt < 2; ++nt) {
#pragma unroll
            for (int r = 0; r < 4; ++r) {
                const int nl = 4 * lg + r;
                const int colg = 32 * w + 16 * nt + l15;
                const size_t n = (size_t)base + nl;
                const float hres = h[n * 128 + colg];
                const float y = (nt == 0 ? acc20[r] : acc21[r]) + b2c[nt] + hres;
                hn_out[n * 128 + colg] = y;
            }
        }
    }
}

extern "C" void kernel_launch(void* const* d_in, const int* in_sizes, int n_in,
                              void* d_out, int out_size, void* d_ws, size_t ws_size,
                              hipStream_t stream)
{
    const float* h     = (const float*)d_in[0];
    const float* pos   = (const float*)d_in[1];
    const int*   eidx  = (const int*)d_in[2];
    const float* eattr = (const float*)d_in[3];
    const float* eW1   = (const float*)d_in[4];
    const float* eb1   = (const float*)d_in[5];
    const float* eW2   = (const float*)d_in[6];
    const float* eb2   = (const float*)d_in[7];
    const float* aW    = (const float*)d_in[8];
    const float* ab    = (const float*)d_in[9];
    const float* nW1   = (const float*)d_in[10];
    const float* nb1   = (const float*)d_in[11];
    const float* nW2   = (const float*)d_in[12];
    const float* nb2   = (const float*)d_in[13];
    const float* pW2   = (const float*)d_in[14];

    float* out    = (float*)d_out;
    float* hn_out = out;                                   // N*128
    float* po_out = out + (size_t)NN * 128;                // N*3
    float* m_out  = po_out + (size_t)NN * 3;               // E*128

    // ws layout
    char* wsb = (char*)d_ws;
    ushort_t* hbf      = (ushort_t*)wsb;                              // N*128 bf16 = 12.8MB
    float*    trans    = (float*)(wsb + 12800000);                    // E*3 f32   = 7.68MB
    int*      deg      = (int*)(wsb + 20480000);                      // N
    int*      row_ptr  = (int*)(wsb + 20680000);                      // N+1
    int*      cursor   = (int*)(wsb + 20880004);                      // N
    int*      edge_list= (int*)(wsb + 21080004);                      // E

    hipMemsetAsync(deg, 0, sizeof(int) * NN, stream);

    cvt_h_kernel<<<(NN * 128 / 8 + 255) / 256, 256, 0, stream>>>(h, hbf);
    hist_kernel<<<(EE + 255) / 256, 256, 0, stream>>>(eidx, deg);
    scan_kernel<<<1, 1024, 0, stream>>>(deg, row_ptr, cursor);
    scatter_kernel<<<(EE + 255) / 256, 256, 0, stream>>>(eidx, cursor, edge_list);

    egcl_edge_kernel<<<512, 256, 0, stream>>>(hbf, pos, eidx, eattr,
                                              eW1, eb1, eW2, eb2, aW, ab, pW2,
                                              m_out, trans);
    egcl_node_kernel<<<1024, 256, 0, stream>>>(hbf, h, m_out, trans,
                                               row_ptr, edge_list, pos,
                                               nW1, nb1, nW2, nb2,
                                               hn_out, po_out);
}

// Round 5
// 571.115 us; speedup vs baseline: 1.2063x; 1.2063x over previous
//
#include <hip/hip_runtime.h>
#include <hip/hip_bf16.h>

#define NN 50000
#define EE 640000
#define FF 128
#define HH 128

typedef unsigned short ushort_t;
using f32x4  = __attribute__((ext_vector_type(4))) float;
using bf16x8 = __attribute__((ext_vector_type(8))) __bf16;
using u16x8  = __attribute__((ext_vector_type(8))) unsigned short;

__device__ __forceinline__ ushort_t f2bf(float f) {
    union { float f; unsigned int i; } v; v.f = f;
    unsigned int r = v.i + 0x7fffu + ((v.i >> 16) & 1u);
    return (ushort_t)(r >> 16);
}
__device__ __forceinline__ float fsilu(float x) { return x / (1.f + __expf(-x)); }
__device__ __forceinline__ float fsig(float x)  { return 1.f / (1.f + __expf(-x)); }

__device__ __forceinline__ u16x8 cvt8(const float* p) {
    float4 a0 = *reinterpret_cast<const float4*>(p);
    float4 a1 = *reinterpret_cast<const float4*>(p + 4);
    u16x8 v;
    v[0] = f2bf(a0.x); v[1] = f2bf(a0.y); v[2] = f2bf(a0.z); v[3] = f2bf(a0.w);
    v[4] = f2bf(a1.x); v[5] = f2bf(a1.y); v[6] = f2bf(a1.z); v[7] = f2bf(a1.w);
    return v;
}

// ---------------------------------------------------------------------------
// h f32 -> bf16 pre-pass
// ---------------------------------------------------------------------------
__global__ void cvt_h_kernel(const float* __restrict__ h, ushort_t* __restrict__ hbf)
{
    const int i = (blockIdx.x * 256 + threadIdx.x) * 8;
    if (i < NN * 128) {
        u16x8 v = cvt8(h + i);
        *reinterpret_cast<u16x8*>(hbf + i) = v;
    }
}

// ---------------------------------------------------------------------------
// CSR build: histogram -> scan -> scatter (also records sorted row ids)
// ---------------------------------------------------------------------------
__global__ void hist_kernel(const int* __restrict__ eidx, int* __restrict__ deg)
{
    const int e = blockIdx.x * 256 + threadIdx.x;
    if (e < EE) atomicAdd(&deg[eidx[e]], 1);
}

__global__ void scan_kernel(const int* __restrict__ deg, int* __restrict__ row_ptr,
                            int* __restrict__ cursor)
{
    __shared__ int sdata[1024];
    const int t = threadIdx.x;
    const int chunk = (NN + 1023) / 1024;
    const int start = t * chunk;
    const int end   = min(start + chunk, NN);
    int s = 0;
    for (int i = start; i < end; ++i) s += deg[i];
    sdata[t] = s;
    __syncthreads();
    for (int off = 1; off < 1024; off <<= 1) {
        int v = (t >= off) ? sdata[t - off] : 0;
        __syncthreads();
        sdata[t] += v;
        __syncthreads();
    }
    int ox = sdata[t] - s;
    for (int i = start; i < end; ++i) {
        row_ptr[i] = ox; cursor[i] = ox; ox += deg[i];
    }
    if (t == 1023) row_ptr[NN] = sdata[1023];
}

__global__ void scatter_kernel(const int* __restrict__ eidx, int* __restrict__ cursor,
                               int* __restrict__ edge_list, int* __restrict__ row_sorted)
{
    const int e = blockIdx.x * 256 + threadIdx.x;
    if (e < EE) {
        const int r = eidx[e];
        const int p = atomicAdd(&cursor[r], 1);
        edge_list[p] = e;
        row_sorted[p] = r;
    }
}

// ---------------------------------------------------------------------------
// Edge kernel, CSR-ordered 64-edge tiles. Computes gated m, writes m_out
// (scatter by original edge id), and aggregates agg / agg_t via segmented
// sums (rows sorted within tile) with few atomics.
// ---------------------------------------------------------------------------
__global__ __launch_bounds__(256, 2) void egcl_edge_kernel(
    const ushort_t* __restrict__ hbf, const float* __restrict__ pos,
    const int* __restrict__ eidx, const float* __restrict__ eattr,
    const int* __restrict__ edge_list, const int* __restrict__ row_sorted,
    const float* __restrict__ w1, const float* __restrict__ b1,
    const float* __restrict__ w2, const float* __restrict__ b2,
    const float* __restrict__ aW, const float* __restrict__ ab,
    const float* __restrict__ pW2,
    float* __restrict__ m_out, float* __restrict__ agg, float* __restrict__ agg_t)
{
    __shared__ __align__(16) ushort_t A_sh[64 * 296];     // 37888 B; alias M2F below
    __shared__ __align__(16) ushort_t M1_sh[64 * 136];
    __shared__ __align__(16) ushort_t M2_sh[64 * 136];
    __shared__ float PD_sh[64][3];
    __shared__ int   ROW_sh[64];
    __shared__ int   EO_sh[64];

    float* M2F = reinterpret_cast<float*>(A_sh);          // [64][132] f32 (33792 B)

    const int tid  = threadIdx.x;
    const int lane = tid & 63;
    const int w    = tid >> 6;
    const int l15  = lane & 15;
    const int lg   = lane >> 4;

    // ---- weights in registers ----
    bf16x8 B1[9][2];
    bf16x8 B2[4][2];
    bf16x8 Bg[4];
    float b1c[2], b2c[2];
    const float abv = ab[0];
#pragma unroll
    for (int nt = 0; nt < 2; ++nt) {
        const int colg = 32 * w + 16 * nt + l15;
        b1c[nt] = b1[colg];
        b2c[nt] = b2[colg];
#pragma unroll
        for (int ks = 0; ks < 9; ++ks) {
            u16x8 v;
#pragma unroll
            for (int j = 0; j < 8; ++j) {
                const int k = 32 * ks + 8 * lg + j;
                v[j] = (k < 265) ? f2bf(w1[k * 128 + colg]) : (ushort_t)0;
            }
            B1[ks][nt] = __builtin_bit_cast(bf16x8, v);
        }
#pragma unroll
        for (int ks = 0; ks < 4; ++ks) {
            u16x8 v;
#pragma unroll
            for (int j = 0; j < 8; ++j) {
                const int k = 32 * ks + 8 * lg + j;
                v[j] = f2bf(w2[k * 128 + colg]);
            }
            B2[ks][nt] = __builtin_bit_cast(bf16x8, v);
        }
    }
#pragma unroll
    for (int ks = 0; ks < 4; ++ks) {
        u16x8 v;
#pragma unroll
        for (int j = 0; j < 8; ++j) {
            const int k = 32 * ks + 8 * lg + j;
            v[j] = (l15 == 0) ? f2bf(aW[k]) : (l15 == 1 ? f2bf(pW2[k]) : (ushort_t)0);
        }
        Bg[ks] = __builtin_bit_cast(bf16x8, v);
    }

    const int ei = tid >> 2;   // CSR slot 0..63
    const int et = tid & 3;    // 4 threads/slot

    for (int tile = blockIdx.x; tile < EE / 64; tile += gridDim.x) {
        // ---- stage (CSR order; rows sorted -> h[row] cache-hot) ----
        {
            const int p  = tile * 64 + ei;
            const int eo = edge_list[p];
            const int r  = row_sorted[p];
            const int c  = eidx[EE + eo];
            const ushort_t* hr = hbf + (size_t)r * 128 + et * 32;
            const ushort_t* hc = hbf + (size_t)c * 128 + et * 32;
#pragma unroll
            for (int q = 0; q < 4; ++q) {
                *reinterpret_cast<u16x8*>(&A_sh[ei * 296 + et * 32 + q * 8]) =
                    *reinterpret_cast<const u16x8*>(hr + q * 8);
                *reinterpret_cast<u16x8*>(&A_sh[ei * 296 + 128 + et * 32 + q * 8]) =
                    *reinterpret_cast<const u16x8*>(hc + q * 8);
            }
            if (et == 0) {
                ROW_sh[ei] = r;
                EO_sh[ei]  = eo;
                const float dx = pos[r * 3 + 0] - pos[c * 3 + 0];
                const float dy = pos[r * 3 + 1] - pos[c * 3 + 1];
                const float dz = pos[r * 3 + 2] - pos[c * 3 + 2];
                PD_sh[ei][0] = dx; PD_sh[ei][1] = dy; PD_sh[ei][2] = dz;
                const float ds = dx * dx + dy * dy + dz * dz;
                u16x8 v0;
                v0[0] = f2bf(ds);
#pragma unroll
                for (int j = 0; j < 7; ++j) v0[1 + j] = f2bf(eattr[(size_t)eo * 8 + j]);
                *reinterpret_cast<u16x8*>(&A_sh[ei * 296 + 256]) = v0;
                u16x8 v1 = {0, 0, 0, 0, 0, 0, 0, 0};
                v1[0] = f2bf(eattr[(size_t)eo * 8 + 7]);
                *reinterpret_cast<u16x8*>(&A_sh[ei * 296 + 264]) = v1;
                u16x8 z = {0, 0, 0, 0, 0, 0, 0, 0};
                *reinterpret_cast<u16x8*>(&A_sh[ei * 296 + 272]) = z;
                *reinterpret_cast<u16x8*>(&A_sh[ei * 296 + 280]) = z;
            }
        }
        __syncthreads();                       // B1: A ready

        // ---- layer 1 ----
#pragma unroll
        for (int s = 0; s < 4; ++s) {
            f32x4 a0 = {0.f, 0.f, 0.f, 0.f};
            f32x4 a1 = {0.f, 0.f, 0.f, 0.f};
#pragma unroll
            for (int ks = 0; ks < 9; ++ks) {
                bf16x8 a = *reinterpret_cast<const bf16x8*>(
                    &A_sh[(16 * s + l15) * 296 + ks * 32 + lg * 8]);
                a0 = __builtin_amdgcn_mfma_f32_16x16x32_bf16(a, B1[ks][0], a0, 0, 0, 0);
                a1 = __builtin_amdgcn_mfma_f32_16x16x32_bf16(a, B1[ks][1], a1, 0, 0, 0);
            }
#pragma unroll
            for (int nt = 0; nt < 2; ++nt) {
#pragma unroll
                for (int rr = 0; rr < 4; ++rr) {
                    const float x = (nt == 0 ? a0[rr] : a1[rr]) + b1c[nt];
                    const int edge = 16 * s + 4 * lg + rr;
                    const int colg = 32 * w + 16 * nt + l15;
                    M1_sh[edge * 136 + colg] = f2bf(fsilu(x));
                }
            }
        }
        __syncthreads();                       // B2: M1 ready, A dead

        // ---- layer 2 ----
        float m2v[4][2][4];
#pragma unroll
        for (int s = 0; s < 4; ++s) {
            f32x4 a0 = {0.f, 0.f, 0.f, 0.f};
            f32x4 a1 = {0.f, 0.f, 0.f, 0.f};
#pragma unroll
            for (int ks = 0; ks < 4; ++ks) {
                bf16x8 a = *reinterpret_cast<const bf16x8*>(
                    &M1_sh[(16 * s + l15) * 136 + ks * 32 + lg * 8]);
                a0 = __builtin_amdgcn_mfma_f32_16x16x32_bf16(a, B2[ks][0], a0, 0, 0, 0);
                a1 = __builtin_amdgcn_mfma_f32_16x16x32_bf16(a, B2[ks][1], a1, 0, 0, 0);
            }
#pragma unroll
            for (int nt = 0; nt < 2; ++nt) {
#pragma unroll
                for (int rr = 0; rr < 4; ++rr) {
                    const float x = (nt == 0 ? a0[rr] : a1[rr]) + b2c[nt];
                    const float sv = fsilu(x);
                    m2v[s][nt][rr] = sv;
                    const int edge = 16 * s + 4 * lg + rr;
                    const int colg = 32 * w + 16 * nt + l15;
                    M2_sh[edge * 136 + colg] = f2bf(sv);
                }
            }
        }
        __syncthreads();                       // B3: M2 ready

        // ---- gate (all subtiles) + trans segmented flush (own subtile) ----
        float gq[4][4];
        float gqw[4], spw[4];
#pragma unroll
        for (int s = 0; s < 4; ++s) {
            f32x4 ga = {0.f, 0.f, 0.f, 0.f};
#pragma unroll
            for (int ks = 0; ks < 4; ++ks) {
                bf16x8 a = *reinterpret_cast<const bf16x8*>(
                    &M2_sh[(16 * s + l15) * 136 + ks * 32 + lg * 8]);
                ga = __builtin_amdgcn_mfma_f32_16x16x32_bf16(a, Bg[ks], ga, 0, 0, 0);
            }
#pragma unroll
            for (int rr = 0; rr < 4; ++rr) {
                const float sa = __shfl(ga[rr], lane & 48);
                const float sp = __shfl(ga[rr], (lane & 48) + 1);
                gq[s][rr] = fsig(sa + abv);
                if (s == w) { gqw[rr] = gq[s][rr]; spw[rr] = sp; }
            }
        }
        if (l15 == 0) {
            int cur = -1; float t0 = 0.f, t1 = 0.f, t2 = 0.f;
#pragma unroll
            for (int rr = 0; rr < 4; ++rr) {
                const int edge = 16 * w + 4 * lg + rr;
                const float t = gqw[rr] * spw[rr];
                const int rid = ROW_sh[edge];
                if (rid != cur) {
                    if (cur >= 0) {
                        atomicAdd(&agg_t[cur * 3 + 0], t0);
                        atomicAdd(&agg_t[cur * 3 + 1], t1);
                        atomicAdd(&agg_t[cur * 3 + 2], t2);
                    }
                    cur = rid; t0 = t1 = t2 = 0.f;
                }
                t0 += PD_sh[edge][0] * t;
                t1 += PD_sh[edge][1] * t;
                t2 += PD_sh[edge][2] * t;
            }
            atomicAdd(&agg_t[cur * 3 + 0], t0);
            atomicAdd(&agg_t[cur * 3 + 1], t1);
            atomicAdd(&agg_t[cur * 3 + 2], t2);
        }

        // ---- gated m: global scatter write + f32 LDS stash for scan ----
#pragma unroll
        for (int s = 0; s < 4; ++s) {
#pragma unroll
            for (int nt = 0; nt < 2; ++nt) {
#pragma unroll
                for (int rr = 0; rr < 4; ++rr) {
                    const int edge = 16 * s + 4 * lg + rr;
                    const int colg = 32 * w + 16 * nt + l15;
                    const float mf = m2v[s][nt][rr] * gq[s][rr];
                    m_out[(size_t)EO_sh[edge] * 128 + colg] = mf;
                    M2F[edge * 132 + colg] = mf;
                }
            }
        }
        __syncthreads();                       // B4: M2F + ROW ready for scan

        // ---- segmented column scan: agg[row] += sum of m rows ----
        {
            const int col = tid & 127;
            const int hf  = tid >> 7;
            const int j0  = hf * 32;
            int cur = ROW_sh[j0];
            float acc = 0.f;
#pragma unroll 4
            for (int j = j0; j < j0 + 32; ++j) {
                const int rid = ROW_sh[j];
                const float v = M2F[j * 132 + col];
                if (rid != cur) {
                    atomicAdd(&agg[(size_t)cur * 128 + col], acc);
                    acc = 0.f; cur = rid;
                }
                acc += v;
            }
            atomicAdd(&agg[(size_t)cur * 128 + col], acc);
        }
        __syncthreads();                       // protect LDS for next tile
    }
}

// ---------------------------------------------------------------------------
// Node kernel: pure streaming. h_new = silu([h|agg]@nW1+nb1)@nW2+nb2+h,
// pos_new = pos + agg_t / max(deg,1)   (deg from row_ptr diff)
// ---------------------------------------------------------------------------
__global__ __launch_bounds__(256, 4) void egcl_node_kernel(
    const ushort_t* __restrict__ hbf, const float* __restrict__ h,
    const float* __restrict__ agg, const float* __restrict__ agg_t,
    const int* __restrict__ row_ptr, const float* __restrict__ pos,
    const float* __restrict__ w1, const float* __restrict__ b1,
    const float* __restrict__ w2, const float* __restrict__ b2,
    float* __restrict__ hn_out, float* __restrict__ pos_out)
{
    __shared__ __align__(16) ushort_t A_sh[16 * 264];
    __shared__ __align__(16) ushort_t M1_sh[16 * 136];

    const int tid  = threadIdx.x;
    const int lane = tid & 63;
    const int w    = tid >> 6;
    const int l15  = lane & 15;
    const int lg   = lane >> 4;

    bf16x8 B1[8][2];
    bf16x8 B2[4][2];
    float b1c[2], b2c[2];
#pragma unroll
    for (int nt = 0; nt < 2; ++nt) {
        const int colg = 32 * w + 16 * nt + l15;
        b1c[nt] = b1[colg];
        b2c[nt] = b2[colg];
#pragma unroll
        for (int ks = 0; ks < 8; ++ks) {
            u16x8 v;
#pragma unroll
            for (int j = 0; j < 8; ++j) {
                const int k = 32 * ks + 8 * lg + j;
                v[j] = f2bf(w1[k * 128 + colg]);
            }
            B1[ks][nt] = __builtin_bit_cast(bf16x8, v);
        }
#pragma unroll
        for (int ks = 0; ks < 4; ++ks) {
            u16x8 v;
#pragma unroll
            for (int j = 0; j < 8; ++j) {
                const int k = 32 * ks + 8 * lg + j;
                v[j] = f2bf(w2[k * 128 + colg]);
            }
            B2[ks][nt] = __builtin_bit_cast(bf16x8, v);
        }
    }

    const int ni = tid >> 4;
    const int nt16 = tid & 15;

    for (int tile = blockIdx.x; tile < NN / 16; tile += gridDim.x) {
        __syncthreads();
        const int base = tile * 16;

        // stage [hbf | bf16(agg)]
        {
            const size_t n = (size_t)base + ni;
            *reinterpret_cast<u16x8*>(&A_sh[ni * 264 + nt16 * 8]) =
                *reinterpret_cast<const u16x8*>(hbf + n * 128 + nt16 * 8);
            u16x8 av = cvt8(agg + n * 128 + nt16 * 8);
            *reinterpret_cast<u16x8*>(&A_sh[ni * 264 + 128 + nt16 * 8]) = av;
        }
        // pos update (threads 0..47)
        if (tid < 48) {
            const int nl = tid / 3, d = tid % 3;
            const size_t n = (size_t)base + nl;
            const float c = (float)(row_ptr[n + 1] - row_ptr[n]);
            pos_out[n * 3 + d] = pos[n * 3 + d] + agg_t[n * 3 + d] / fmaxf(c, 1.f);
        }
        __syncthreads();

        f32x4 acc10 = {0.f, 0.f, 0.f, 0.f};
        f32x4 acc11 = {0.f, 0.f, 0.f, 0.f};
#pragma unroll
        for (int ks = 0; ks < 8; ++ks) {
            bf16x8 a = *reinterpret_cast<const bf16x8*>(&A_sh[l15 * 264 + ks * 32 + lg * 8]);
            acc10 = __builtin_amdgcn_mfma_f32_16x16x32_bf16(a, B1[ks][0], acc10, 0, 0, 0);
            acc11 = __builtin_amdgcn_mfma_f32_16x16x32_bf16(a, B1[ks][1], acc11, 0, 0, 0);
        }
#pragma unroll
        for (int nt = 0; nt < 2; ++nt) {
#pragma unroll
            for (int r = 0; r < 4; ++r) {
                const float x = (nt == 0 ? acc10[r] : acc11[r]) + b1c[nt];
                const int nl = 4 * lg + r;
                const int colg = 32 * w + 16 * nt + l15;
                M1_sh[nl * 136 + colg] = f2bf(fsilu(x));
            }
        }
        __syncthreads();

        f32x4 acc20 = {0.f, 0.f, 0.f, 0.f};
        f32x4 acc21 = {0.f, 0.f, 0.f, 0.f};
#pragma unroll
        for (int ks = 0; ks < 4; ++ks) {
            bf16x8 a = *reinterpret_cast<const bf16x8*>(&M1_sh[l15 * 136 + ks * 32 + lg * 8]);
            acc20 = __builtin_amdgcn_mfma_f32_16x16x32_bf16(a, B2[ks][0], acc20, 0, 0, 0);
            acc21 = __builtin_amdgcn_mfma_f32_16x16x32_bf16(a, B2[ks][1], acc21, 0, 0, 0);
        }
#pragma unroll
        for (int nt = 0; nt < 2; ++nt) {
#pragma unroll
            for (int r = 0; r < 4; ++r) {
                const int nl = 4 * lg + r;
                const int colg = 32 * w + 16 * nt + l15;
                const size_t n = (size_t)base + nl;
                const float hres = h[n * 128 + colg];
                const float y = (nt == 0 ? acc20[r] : acc21[r]) + b2c[nt] + hres;
                hn_out[n * 128 + colg] = y;
            }
        }
    }
}

extern "C" void kernel_launch(void* const* d_in, const int* in_sizes, int n_in,
                              void* d_out, int out_size, void* d_ws, size_t ws_size,
                              hipStream_t stream)
{
    const float* h     = (const float*)d_in[0];
    const float* pos   = (const float*)d_in[1];
    const int*   eidx  = (const int*)d_in[2];
    const float* eattr = (const float*)d_in[3];
    const float* eW1   = (const float*)d_in[4];
    const float* eb1   = (const float*)d_in[5];
    const float* eW2   = (const float*)d_in[6];
    const float* eb2   = (const float*)d_in[7];
    const float* aW    = (const float*)d_in[8];
    const float* ab    = (const float*)d_in[9];
    const float* nW1   = (const float*)d_in[10];
    const float* nb1   = (const float*)d_in[11];
    const float* nW2   = (const float*)d_in[12];
    const float* nb2   = (const float*)d_in[13];
    const float* pW2   = (const float*)d_in[14];

    float* out    = (float*)d_out;
    float* hn_out = out;                                   // N*128
    float* po_out = out + (size_t)NN * 128;                // N*3
    float* m_out  = po_out + (size_t)NN * 3;               // E*128

    // ws layout (bytes)
    char* wsb = (char*)d_ws;
    float* agg        = (float*)(wsb + 0);                 // 25,600,000
    float* agg_t      = (float*)(wsb + 25600000);          //    600,000
    int*   deg        = (int*)  (wsb + 26200000);          //    200,000
    int*   row_ptr    = (int*)  (wsb + 26400000);          //    200,004
    int*   cursor     = (int*)  (wsb + 26600256);          //    200,000
    int*   edge_list  = (int*)  (wsb + 26800256);          //  2,560,000
    int*   row_sorted = (int*)  (wsb + 29360256);          //  2,560,000
    ushort_t* hbf     = (ushort_t*)(wsb + 31920256);       // 12,800,000

    // zero agg + agg_t + deg in one shot (contiguous)
    hipMemsetAsync(wsb, 0, 26400000, stream);

    cvt_h_kernel<<<(NN * 128 / 8 + 255) / 256, 256, 0, stream>>>(h, hbf);
    hist_kernel<<<(EE + 255) / 256, 256, 0, stream>>>(eidx, deg);
    scan_kernel<<<1, 1024, 0, stream>>>(deg, row_ptr, cursor);
    scatter_kernel<<<(EE + 255) / 256, 256, 0, stream>>>(eidx, cursor, edge_list, row_sorted);

    egcl_edge_kernel<<<512, 256, 0, stream>>>(hbf, pos, eidx, eattr,
                                              edge_list, row_sorted,
                                              eW1, eb1, eW2, eb2, aW, ab, pW2,
                                              m_out, agg, agg_t);
    egcl_node_kernel<<<1024, 256, 0, stream>>>(hbf, h, agg, agg_t, row_ptr, pos,
                                               nW1, nb1, nW2, nb2,
                                               hn_out, po_out);
}